// Round 4
// baseline (267.833 us; speedup 1.0000x reference)
//
#include <hip/hip_runtime.h>
#include <math.h>

// x: (16, 512, 512, 8) float32 NHWC. float4 "granule" = 4 channels.
// Row = 512 w * 2 granules = 1024 granules. Block owns 256 consecutive
// granules (128 pixels) of one row-strip, HPT=8 rows tall.
// Stage (HPT+2) x 260 granules into LDS ONCE (w/h out-of-image -> -inf),
// then each thread serves its 3x3 window from LDS with register rolling:
// 3 ds_read_b128 per output instead of 9 global loads (round-1) or 30
// up-front global loads (round-3). Cuts L1 traffic 3x and vmem instrs 2x.

constexpr int Hdim = 512;
constexpr int Wdim = 512;
constexpr int HPT  = 8;
constexpr int ROWS = HPT + 2;
constexpr int GPB  = 256;             // granules owned per block
constexpr int HALO = 2;               // +/- 1 pixel = 2 granules
constexpr int LW   = GPB + 2 * HALO;  // 260 granules per LDS row
constexpr int ROWG = Wdim * 2;        // 1024 granules per image row

__device__ __forceinline__ float4 f4max(float4 a, float4 b) {
    return make_float4(fmaxf(a.x,b.x), fmaxf(a.y,b.y), fmaxf(a.z,b.z), fmaxf(a.w,b.w));
}
__device__ __forceinline__ float4 f4sel(bool ok, float4 v, float4 e) {
    return make_float4(ok ? v.x : e.x, ok ? v.y : e.y, ok ? v.z : e.z, ok ? v.w : e.w);
}

__global__ __launch_bounds__(256) void nms_kernel(
    const float4* __restrict__ x,
    const unsigned char* __restrict__ mask_bytes,
    float4* __restrict__ out)
{
    __shared__ float4 lds[ROWS][LW];   // 10 * 260 * 16 B = 41600 B

    // ---- Decode 3x3 boolean mask robustly (int32 vs 1-byte bool layout).
    const int* mi = (const int*)mask_bytes;
    bool intlay = true;
    #pragma unroll
    for (int i = 0; i < 9; ++i) { int v = mi[i]; intlay = intlay && (v == 0 || v == 1); }
    bool m[9];
    #pragma unroll
    for (int i = 0; i < 9; ++i) m[i] = intlay ? (mi[i] != 0) : (mask_bytes[i] != 0);

    const float4 NEG = make_float4(-INFINITY, -INFINITY, -INFINITY, -INFINITY);

    int t   = threadIdx.x;
    int bid = blockIdx.x;
    int gb  = bid & 3;           // 4 blocks span one image row (1024 granules)
    int hg  = (bid >> 2) & 63;   // 64 h-strips
    int n   = bid >> 8;          // 16 images
    int g0  = gb * GPB;
    int h0  = hg * HPT;

    // ---- Stage ROWS x LW granules, -inf outside the image (like jnp.pad).
    #pragma unroll
    for (int r = 0; r < ROWS; ++r) {
        int hr  = h0 - 1 + r;
        int hrc = hr < 0 ? 0 : (hr > Hdim - 1 ? Hdim - 1 : hr);
        bool hok = (hr == hrc);                       // block-uniform
        long rowbase = ((long)(n * Hdim + hrc)) * ROWG;
        {
            int gc  = g0 - HALO + t;
            int gcc = gc < 0 ? 0 : (gc > ROWG - 1 ? ROWG - 1 : gc);
            float4 v = x[rowbase + gcc];
            lds[r][t] = f4sel(hok && (gc == gcc), v, NEG);
        }
        if (t < 2 * HALO) {                           // 4 halo granules
            int c   = GPB + t;
            int gc  = g0 - HALO + c;
            int gcc = gc < 0 ? 0 : (gc > ROWG - 1 ? ROWG - 1 : gc);
            float4 v = x[rowbase + gcc];
            lds[r][c] = f4sel(hok && (gc == gcc), v, NEG);
        }
    }
    __syncthreads();

    // ---- Compute with a rolling 3-row register window from LDS.
    // Thread t owns granule g0+t => LDS col t+2; a=col t, b=t+2, c=t+4.
    float4 A0 = lds[0][t], B0 = lds[0][t + 2], C0 = lds[0][t + 4];
    float4 A1 = lds[1][t], B1 = lds[1][t + 2], C1 = lds[1][t + 4];

    long obase = ((long)(n * Hdim + h0)) * ROWG + g0 + t;

    #pragma unroll
    for (int s = 0; s < HPT; ++s) {
        float4 A2 = lds[s + 2][t], B2 = lds[s + 2][t + 2], C2 = lds[s + 2][t + 4];

        float4 va = NEG, vb = NEG, vc = NEG;
        if (m[0]) va = f4max(va, A0);
        if (m[3]) va = f4max(va, A1);
        if (m[6]) va = f4max(va, A2);
        if (m[1]) vb = f4max(vb, B0);
        if (m[4]) vb = f4max(vb, B1);
        if (m[7]) vb = f4max(vb, B2);
        if (m[2]) vc = f4max(vc, C0);
        if (m[5]) vc = f4max(vc, C1);
        if (m[8]) vc = f4max(vc, C2);

        float4 mm = f4max(f4max(va, vb), vc);
        float4 ctr = B1;
        float4 o;
        o.x = (ctr.x > mm.x) ? ctr.x : 0.0f;
        o.y = (ctr.y > mm.y) ? ctr.y : 0.0f;
        o.z = (ctr.z > mm.z) ? ctr.z : 0.0f;
        o.w = (ctr.w > mm.w) ? ctr.w : 0.0f;
        out[obase + s * ROWG] = o;

        A0 = A1; A1 = A2;
        B0 = B1; B1 = B2;
        C0 = C1; C1 = C2;
    }
}

extern "C" void kernel_launch(void* const* d_in, const int* in_sizes, int n_in,
                              void* d_out, int out_size, void* d_ws, size_t ws_size,
                              hipStream_t stream) {
    const float4* x = (const float4*)d_in[0];
    const unsigned char* mask = (const unsigned char*)d_in[1];
    float4* out = (float4*)d_out;

    int grid = 16 * (Hdim / HPT) * (ROWG / GPB);  // 16*64*4 = 4096 blocks
    nms_kernel<<<grid, 256, 0, stream>>>(x, mask, out);
}

// Round 5
// 234.929 us; speedup vs baseline: 1.1401x; 1.1401x over previous
//
#include <hip/hip_runtime.h>
#include <math.h>

// x: (16, 512, 512, 8) float32 NHWC. float4 granule idx:
//   idx = ((n*512 + h)*512 + w)*2 + c4
// One output granule per thread (max occupancy), but ALL 9 stencil loads
// are issued branchlessly up front (clamped addresses; validity applied
// after the loads as -inf selects). Goal: high waves/CU AND ~9 KB of
// outstanding loads per wave -> latency-covered, HBM-bound.

constexpr int Hdim = 512;
constexpr int Wdim = 512;
constexpr int ROWG = Wdim * 2;   // granules per image row

__device__ __forceinline__ float4 f4max(float4 a, float4 b) {
    return make_float4(fmaxf(a.x,b.x), fmaxf(a.y,b.y), fmaxf(a.z,b.z), fmaxf(a.w,b.w));
}

__global__ __launch_bounds__(256) void nms_kernel(
    const float4* __restrict__ x,
    const unsigned char* __restrict__ mask_bytes,
    float4* __restrict__ out,
    int total4)
{
    // ---- Decode 3x3 boolean mask robustly (int32 vs 1-byte bool layout).
    const int* mi = (const int*)mask_bytes;
    bool intlay = true;
    #pragma unroll
    for (int i = 0; i < 9; ++i) { int v = mi[i]; intlay = intlay && (v == 0 || v == 1); }
    bool m[9];
    #pragma unroll
    for (int i = 0; i < 9; ++i) m[i] = intlay ? (mi[i] != 0) : (mask_bytes[i] != 0);

    int idx = blockIdx.x * blockDim.x + threadIdx.x;
    if (idx >= total4) return;

    int w = (idx >> 1) & (Wdim - 1);
    int h = (idx >> 10) & (Hdim - 1);

    // Clamped relative offsets (granules) + validity flags, all branchless.
    bool hup = (h > 0), hdn = (h < Hdim - 1);
    bool wlf = (w > 0), wrt = (w < Wdim - 1);
    int oN = hup ? -ROWG : 0;
    int oS = hdn ?  ROWG : 0;
    int oW = wlf ? -2 : 0;
    int oE = wrt ?  2 : 0;

    // ---- Issue all 9 loads back-to-back (independent, no control flow).
    float4 vNW = x[idx + oN + oW];
    float4 vN  = x[idx + oN];
    float4 vNE = x[idx + oN + oE];
    float4 vW  = x[idx + oW];
    float4 vC  = x[idx];
    float4 vE  = x[idx + oE];
    float4 vSW = x[idx + oS + oW];
    float4 vS  = x[idx + oS];
    float4 vSE = x[idx + oS + oE];

    bool k0 = m[0] && hup && wlf;
    bool k1 = m[1] && hup;
    bool k2 = m[2] && hup && wrt;
    bool k3 = m[3] && wlf;
    bool k4 = m[4];
    bool k5 = m[5] && wrt;
    bool k6 = m[6] && hdn && wlf;
    bool k7 = m[7] && hdn;
    bool k8 = m[8] && hdn && wrt;

    const float4 NEG = make_float4(-INFINITY, -INFINITY, -INFINITY, -INFINITY);
    float4 mm = NEG;
    if (k0) mm = f4max(mm, vNW);
    if (k1) mm = f4max(mm, vN);
    if (k2) mm = f4max(mm, vNE);
    if (k3) mm = f4max(mm, vW);
    if (k4) mm = f4max(mm, vC);
    if (k5) mm = f4max(mm, vE);
    if (k6) mm = f4max(mm, vSW);
    if (k7) mm = f4max(mm, vS);
    if (k8) mm = f4max(mm, vSE);

    float4 o;
    o.x = (vC.x > mm.x) ? vC.x : 0.0f;
    o.y = (vC.y > mm.y) ? vC.y : 0.0f;
    o.z = (vC.z > mm.z) ? vC.z : 0.0f;
    o.w = (vC.w > mm.w) ? vC.w : 0.0f;
    out[idx] = o;
}

extern "C" void kernel_launch(void* const* d_in, const int* in_sizes, int n_in,
                              void* d_out, int out_size, void* d_ws, size_t ws_size,
                              hipStream_t stream) {
    const float4* x = (const float4*)d_in[0];
    const unsigned char* mask = (const unsigned char*)d_in[1];
    float4* out = (float4*)d_out;

    int total4 = out_size / 4;               // 8,388,608
    int block = 256;
    int grid = (total4 + block - 1) / block; // 32768 blocks
    nms_kernel<<<grid, block, 0, stream>>>(x, mask, out, total4);
}